// Round 11
// baseline (633.711 us; speedup 1.0000x reference)
//
#include <hip/hip_runtime.h>
#include <hip/hip_fp16.h>

// GCN (3× GCNConv, PyG semantics) on MI355X.
// Pipeline per call (9 dispatches):
//   0. hipMemsetAsync - zero bucket cursors
//   1. k_front   - blocks [0,nEB): edge slab scatter; rest: mm1 x@W1 (inline
//                  W1->fp16), output in SLICE layout [slice][node][16] fp16
//   2. k_slabdeg - per-bucket deg accumulate -> dinv; block 0 scans counts->bbase
//   3. k_csrw    - bucket CSR build (normalized weights) ∥ W2/W3 -> fp16T
//   4. k_agg_s   - SLICED aggregation L1: slice = blockIdx%8 pins slice s to
//                  XCD s (round-robin dispatch heuristic); slice table 3.2MB
//                  fits the XCD-private 4MB L2 -> gathers become L2 hits
//   5. mm2 (sliced A -> sliced C), 6. k_agg_s L2, 7. mm3 (sliced A -> row-major
//   64-col table), 8. k_agg<64> unsliced -> f32 d_out
// Old unsliced agg measured at the fabric ceiling: 200MB FETCH (=table x 8 XCD
// compulsory L2 fill) @ ~3.6 TB/s. Slicing removes the x8 multiplier.

#define F_IN 128
#define HID  128
#define N_CLS 64

#define EDGE_CHUNK 8192   // edges per block in bscatter (32/thread)
#define BCAP 6144         // stage slab capacity per bucket (max count ~4400)

typedef _Float16 h8 __attribute__((ext_vector_type(8)));
typedef float f32x4 __attribute__((ext_vector_type(4)));

// ---------------- MFMA matmul body ----------------
// C[nrows][BN] (fp16) = A[nrows][128] @ W[128][BN], f32 accum.
// block = 64 rows, 4 waves x 16 rows. lw/lc carved from caller smem.
// CVTW:   stage W from f32 k-major source (transpose+convert); else fp16 WT.
// ASLICE: A is fp16 in slice layout [k/16][row][16] (stride nrows*16).
// CSLICE: C written in slice layout [n/16][row][16]; else row-major [row][BN].

template <int BN, typename TA, bool CVTW, bool ASLICE, bool CSLICE>
__device__ __forceinline__
void mm_body(const TA* __restrict__ A, const float* __restrict__ Wsrc,
             const _Float16* __restrict__ WT, __half* __restrict__ C,
             int nrows, int bid, char* smem) {
    constexpr int K   = 128;
    constexpr int NCT = BN / 16;          // col tiles per wave: 8 or 4
    constexpr int KP  = K + 8;            // LDS W row stride (halves)
    constexpr int CP  = BN + 8;           // LDS C row stride (halves)
    _Float16* lw = (_Float16*)smem;                         // BN*KP halves
    _Float16* lc = (_Float16*)(smem + (size_t)BN * KP * 2); // 64*CP halves
    const int tid  = threadIdx.x;
    const int wave = tid >> 6;
    const int lane = tid & 63;
    const int bm0  = bid * 64;

    if constexpr (CVTW) {
        // Wsrc[k][BN] f32 -> lw[n*KP+k] fp16 (coalesced reads: n fastest)
        for (int c = tid; c < BN * K; c += 256) {
            int n = c & (BN - 1);
            int k = c / BN;
            lw[n * KP + k] = (_Float16)Wsrc[k * BN + n];
        }
    } else {
        for (int c = tid; c < BN * 16; c += 256) {
            int n = c >> 4, k = (c & 15) * 8;
            *(h8*)&lw[n * KP + k] = *(const h8*)&WT[n * 128 + k];
        }
    }
    __syncthreads();

    f32x4 acc[NCT];
#pragma unroll
    for (int ct = 0; ct < NCT; ++ct)
#pragma unroll
        for (int i = 0; i < 4; ++i) acc[ct][i] = 0.0f;

    const int row = bm0 + wave * 16 + (lane & 15);
    const int kb  = (lane >> 4) * 8;
    const bool rok = row < nrows;

#pragma unroll
    for (int kk = 0; kk < 4; ++kk) {
        const int k0 = kk * 32 + kb;
        h8 va;
        if (rok) {
            if constexpr (__is_same(TA, float)) {
                float4 f0 = *(const float4*)&A[(size_t)row * K + k0];
                float4 f1 = *(const float4*)&A[(size_t)row * K + k0 + 4];
                va[0] = (_Float16)f0.x; va[1] = (_Float16)f0.y;
                va[2] = (_Float16)f0.z; va[3] = (_Float16)f0.w;
                va[4] = (_Float16)f1.x; va[5] = (_Float16)f1.y;
                va[6] = (_Float16)f1.z; va[7] = (_Float16)f1.w;
            } else if constexpr (ASLICE) {
                va = *(const h8*)&A[((size_t)(k0 >> 4) * nrows + row) * 16 + (k0 & 15)];
            } else {
                va = *(const h8*)&A[(size_t)row * K + k0];
            }
        } else {
#pragma unroll
            for (int i = 0; i < 8; ++i) va[i] = (_Float16)0.0f;
        }
#pragma unroll
        for (int ct = 0; ct < NCT; ++ct) {
            h8 vb = *(const h8*)&lw[(ct * 16 + (lane & 15)) * KP + k0];
            acc[ct] = __builtin_amdgcn_mfma_f32_16x16x32_f16(va, vb, acc[ct], 0, 0, 0);
        }
    }

    // stage C tile (fp16) in LDS, then coalesced copy-out
#pragma unroll
    for (int ct = 0; ct < NCT; ++ct)
#pragma unroll
        for (int r = 0; r < 4; ++r)
            lc[(wave * 16 + (lane >> 4) * 4 + r) * CP + ct * 16 + (lane & 15)] =
                (_Float16)acc[ct][r];
    __syncthreads();

    constexpr int NCH = (64 * BN / 8) / 256;   // 8-half chunks per thread
#pragma unroll
    for (int i = 0; i < NCH; ++i) {
        int c = i * 256 + tid;
        int r = c / (BN / 8), col = (c % (BN / 8)) * 8;
        int grow = bm0 + r;
        if (grow < nrows) {
            if constexpr (CSLICE) {
                *(h8*)&C[((size_t)(col >> 4) * nrows + grow) * 16 + (col & 15)] =
                    *(const h8*)&lc[r * CP + col];
            } else {
                *(h8*)&C[(size_t)grow * BN + col] = *(const h8*)&lc[r * CP + col];
            }
        }
    }
}

// ---------------- edge slab scatter body ----------------

__device__ __forceinline__
void bscatter_body(const int* __restrict__ src, const int* __restrict__ dst,
                   const float* __restrict__ w, int* __restrict__ cursor,
                   int2* __restrict__ stage, int E, int bid, char* smem) {
    int* lcnt  = (int*)smem;            // 512 ints
    int* lbase = (int*)(smem + 2048);   // 512 ints
    const int t = threadIdx.x;
    for (int i = t; i < 512; i += 256) lcnt[i] = 0;
    __syncthreads();
    const int base = bid * EDGE_CHUNK;
    int d[32];
#pragma unroll
    for (int i = 0; i < 32; ++i) {
        int e = base + i * 256 + t;
        d[i] = (e < E) ? dst[e] : -1;
        if (d[i] >= 0) atomicAdd(&lcnt[d[i] >> 8], 1);
    }
    __syncthreads();
    for (int i = t; i < 512; i += 256) {
        int c = lcnt[i];
        lbase[i] = (c > 0) ? atomicAdd(&cursor[i], c) : 0;
        lcnt[i] = 0;
    }
    __syncthreads();
#pragma unroll
    for (int i = 0; i < 32; ++i) {
        int e = base + i * 256 + t;
        if (e >= E) continue;
        int dd = d[i];
        int b  = dd >> 8;
        int p  = lbase[b] + atomicAdd(&lcnt[b], 1);
        if (p < BCAP)   // overflow guard (cannot trigger for this input)
            stage[(size_t)b * BCAP + p] =
                make_int2(src[e] | ((dd & 255) << 20), __float_as_int(w[e]));
    }
}

// ---------------- k_front: bscatter blocks + layer-1 matmul blocks ----------------

#define SMEM_FRONT ((HID * (128 + 8) + 64 * (HID + 8)) * 2)   // 52224 B

__launch_bounds__(256)
__global__ void k_front(const int* __restrict__ src, const int* __restrict__ dst,
                        const float* __restrict__ w, int* __restrict__ cursor,
                        int2* __restrict__ stage, int E,
                        const float* __restrict__ x, const float* __restrict__ W1,
                        __half* __restrict__ bufS, int nrows, int nEB) {
    __shared__ __align__(16) char smem[SMEM_FRONT];
    if ((int)blockIdx.x < nEB)
        bscatter_body(src, dst, w, cursor, stage, E, blockIdx.x, smem);
    else
        mm_body<HID, float, true, false, true>(x, W1, nullptr, bufS, nrows,
                                               blockIdx.x - nEB, smem);
}

// ---------------- k_slabdeg ----------------

__global__ void k_slabdeg(const int2* __restrict__ stage, const int* __restrict__ cursor,
                          float* __restrict__ dinv, int* __restrict__ bbase,
                          int n, int NB, int E) {
    __shared__ float degf[256];
    __shared__ int   sh[512];
    const int b = blockIdx.x, t = threadIdx.x;
    if (t < 256) degf[t] = 0.0f;
    __syncthreads();
    const int cnt0 = cursor[b];
    const int cnt  = (cnt0 < BCAP) ? cnt0 : BCAP;
    const int2* sl = stage + (size_t)b * BCAP;
    for (int j = t; j < cnt; j += 512) {
        int2 s = sl[j];
        atomicAdd(&degf[s.x >> 20], __int_as_float(s.y));
    }
    __syncthreads();
    const int node = b * 256 + t;
    if (t < 256 && node < n) dinv[node] = rsqrtf(1.0f + degf[t]);   // self-loop w=1

    if (b == 0) {   // exclusive scan of counts -> bbase (NB <= 512)
        sh[t] = (t < NB) ? min(cursor[t], BCAP) : 0;
        __syncthreads();
        for (int off = 1; off < 512; off <<= 1) {
            int x2 = (t >= off) ? sh[t - off] : 0;
            __syncthreads();
            sh[t] += x2;
            __syncthreads();
        }
        if (t < NB) bbase[t] = (t == 0) ? 0 : sh[t - 1];
        if (t == 0) bbase[NB] = E;
    }
}

// ---------------- k_csrw: bucket CSR build + W2/W3 convert ----------------

__launch_bounds__(256)
__global__ void k_csrw(const int2* __restrict__ stage, const int* __restrict__ bbase,
                       const float* __restrict__ dinv,
                       int* __restrict__ row_ptr, int2* __restrict__ csr,
                       int n, int E,
                       const float* __restrict__ W2, const float* __restrict__ W3,
                       _Float16* __restrict__ W2T, _Float16* __restrict__ W3T, int NB) {
    __shared__ int scn[256];
    __shared__ int cur[256];
    const int t = threadIdx.x;
    if ((int)blockIdx.x >= NB) {         // weight convert blocks
        int id = ((int)blockIdx.x - NB) * 256 + t;      // 0..24575
        if (id < 16384) {                // W2: 128x128
            int n2 = id >> 7, k = id & 127;
            W2T[n2 * 128 + k] = (_Float16)W2[k * 128 + n2];
        } else {                         // W3: 128x64
            int i = id - 16384;
            int n3 = i >> 7, k = i & 127;
            W3T[n3 * 128 + k] = (_Float16)W3[k * 64 + n3];
        }
        return;
    }
    const int b = blockIdx.x;
    const int beg = bbase[b];
    const int cnt = bbase[b + 1] - beg;
    const int2* sl = stage + (size_t)b * BCAP;
    scn[t] = 0;
    __syncthreads();
    for (int j = t; j < cnt; j += 256)
        atomicAdd(&scn[sl[j].x >> 20], 1);
    __syncthreads();
    int own = scn[t];
    __syncthreads();
    for (int off = 1; off < 256; off <<= 1) {          // inclusive scan
        int x2 = (t >= off) ? scn[t - off] : 0;
        __syncthreads();
        scn[t] += x2;
        __syncthreads();
    }
    const int excl = scn[t] - own;
    const int node = b * 256 + t;
    if (node < n) row_ptr[node] = beg + excl;
    cur[t] = excl;
    __syncthreads();
    for (int j = t; j < cnt; j += 256) {
        int2 s = sl[j];
        int dlow  = s.x >> 20;
        int srcid = s.x & 0xFFFFF;
        float nw  = dinv[srcid] * __int_as_float(s.y);
        int pos = beg + atomicAdd(&cur[dlow], 1);
        csr[pos] = make_int2(srcid, __float_as_int(nw));
    }
    if (b == 0 && t == 0) row_ptr[n] = E;
}

// ---------------- standalone matmul kernel (layers 2,3) ----------------

template <int BN, bool CSLICE>
__launch_bounds__(256)
__global__ void k_mm_mfma(const _Float16* __restrict__ A, const _Float16* __restrict__ WT,
                          __half* __restrict__ C, int nrows) {
    __shared__ __align__(16) char smem[(BN * (128 + 8) + 64 * (BN + 8)) * 2];
    mm_body<BN, _Float16, false, true, CSLICE>(A, nullptr, WT, C, nrows,
                                               blockIdx.x, smem);
}

// ---------------- SLICED CSR aggregation (128-col tables, layers 1-2) ----------------
// slice = blockIdx%8 -> XCD pin (round-robin dispatch heuristic); slice table
// [slice][node][16] fp16 = 3.2MB, L2-resident per XCD. One wave per node;
// 8-lane groups each own an edge (8 in flight), half2/lane, shfl_xor reduce.
//   out = dn * (sum_j nw_j * x[s_j] + dn * x[node]) + bias   (out also sliced)

template <bool RELU>
__launch_bounds__(256)
__global__ void k_agg_s(const __half* __restrict__ T, const int* __restrict__ row_ptr,
                        const int2* __restrict__ csr, const float* __restrict__ dinv,
                        const float* __restrict__ bias, __half* __restrict__ out,
                        int n, int N) {
    const int slice = blockIdx.x & 7;
    const int grp   = blockIdx.x >> 3;
    int node = grp * 4 + (threadIdx.x >> 6);
    if (node >= n) return;
    node = __builtin_amdgcn_readfirstlane(node);
    const int lane = threadIdx.x & 63;
    const int sub  = lane >> 3;          // edge-group 0..7
    const int c2   = lane & 7;           // col pair within slice
    const float dn = dinv[node];
    const int beg = row_ptr[node];
    const int total = row_ptr[node + 1] - beg + 1;   // +1 for self
    const __half* tb = T + (size_t)slice * N * 16;

    float a0 = 0.0f, a1 = 0.0f;
    for (int i = sub; i < total; i += 8) {
        int sidx; float w;
        if (i == 0) { sidx = node; w = dn; }
        else { int2 e = csr[beg + i - 1]; sidx = e.x; w = __int_as_float(e.y); }
        __half2 v = *(const __half2*)&tb[(size_t)sidx * 16 + c2 * 2];
        a0 = fmaf(w, __low2float(v), a0);
        a1 = fmaf(w, __high2float(v), a1);
    }
#pragma unroll
    for (int m = 8; m <= 32; m <<= 1) {
        a0 += __shfl_xor(a0, m, 64);
        a1 += __shfl_xor(a1, m, 64);
    }
    if (sub == 0) {
        float2 bb = *(const float2*)&bias[slice * 16 + c2 * 2];
        a0 = fmaf(dn, a0, bb.x);
        a1 = fmaf(dn, a1, bb.y);
        if (RELU) { a0 = fmaxf(a0, 0.0f); a1 = fmaxf(a1, 0.0f); }
        *(__half2*)&out[((size_t)slice * N + node) * 16 + c2 * 2] =
            __floats2half2_rn(a0, a1);
    }
}

// ---------------- unsliced aggregation (layer 3: 64-col table, f32 out) ----------------

template <int NCOL, bool RELU>
__launch_bounds__(256)
__global__ void k_agg(const __half* __restrict__ XW, const int* __restrict__ row_ptr,
                      const int2* __restrict__ csr,
                      const float* __restrict__ dinv, const float* __restrict__ bias,
                      float* __restrict__ out, int n) {
    int wid  = (blockIdx.x * blockDim.x + threadIdx.x) >> 6;
    int lane = threadIdx.x & 63;
    if (wid >= n) return;
    const int node = __builtin_amdgcn_readfirstlane(wid);
    const float dn  = dinv[node];
    const int  beg  = row_ptr[node];
    const int  end  = row_ptr[node + 1];

    float a0 = dn * __half2float(XW[(size_t)node * NCOL + lane]);

    int j = beg;
    for (; j + 4 <= end; j += 4) {
        int2 e0 = csr[j + 0], e1 = csr[j + 1], e2 = csr[j + 2], e3 = csr[j + 3];
        float w0 = __int_as_float(e0.y), w1 = __int_as_float(e1.y);
        float w2 = __int_as_float(e2.y), w3 = __int_as_float(e3.y);
        float v0 = __half2float(XW[(size_t)e0.x * NCOL + lane]);
        float v1 = __half2float(XW[(size_t)e1.x * NCOL + lane]);
        float v2 = __half2float(XW[(size_t)e2.x * NCOL + lane]);
        float v3 = __half2float(XW[(size_t)e3.x * NCOL + lane]);
        a0 = fmaf(w0, v0, a0);
        a0 = fmaf(w1, v1, a0);
        a0 = fmaf(w2, v2, a0);
        a0 = fmaf(w3, v3, a0);
    }
    for (; j < end; ++j) {
        int2 e = csr[j];
        a0 = fmaf(__int_as_float(e.y),
                  __half2float(XW[(size_t)e.x * NCOL + lane]), a0);
    }

    a0 = fmaf(dn, a0, bias[lane]);
    if (RELU) a0 = fmaxf(a0, 0.0f);
    out[(size_t)node * NCOL + lane] = a0;
}

// ---------------- launch ----------------

extern "C" void kernel_launch(void* const* d_in, const int* in_sizes, int n_in,
                              void* d_out, int out_size, void* d_ws, size_t ws_size,
                              hipStream_t stream) {
    const float* x  = (const float*)d_in[0];
    const int*   ei = (const int*)d_in[1];
    const float* ea = (const float*)d_in[2];
    const float* W1 = (const float*)d_in[3];
    const float* b1 = (const float*)d_in[4];
    const float* W2 = (const float*)d_in[5];
    const float* b2 = (const float*)d_in[6];
    const float* W3 = (const float*)d_in[7];
    const float* b3 = (const float*)d_in[8];

    const int N = in_sizes[0] / F_IN;   // 100000
    const int E = in_sizes[1] / 2;      // 1600000
    const int* src = ei;
    const int* dst = ei + E;
    const int NB = (N + 255) / 256;     // 391 buckets (<= 512 assumed)

    // workspace carve-up (256B aligned)
    char* ws = (char*)d_ws;
    size_t off = 0;
    auto alloc = [&](size_t bytes) -> void* {
        void* p = ws + off;
        off += (bytes + 255) & ~(size_t)255;
        return p;
    };
    __half*    bufS1   = (__half*)   alloc((size_t)N * HID * sizeof(__half)); // sliced tables
    __half*    bufS2   = (__half*)   alloc((size_t)N * HID * sizeof(__half)); // sliced h
    float*     dinv    = (float*)    alloc((size_t)N * sizeof(float));
    int*       row_ptr = (int*)      alloc((size_t)(N + 1) * sizeof(int));
    int2*      csr     = (int2*)     alloc((size_t)E * sizeof(int2));
    int2*      stage   = (int2*)     alloc((size_t)NB * BCAP * sizeof(int2)); // 19.2 MB slabs
    int*       cursor  = (int*)      alloc((size_t)NB * sizeof(int));
    int*       bbase   = (int*)      alloc((size_t)(NB + 1) * sizeof(int));
    _Float16*  W2T     = (_Float16*) alloc((size_t)128 * 128 * sizeof(_Float16));
    _Float16*  W3T     = (_Float16*) alloc((size_t)64 * 128 * sizeof(_Float16));
    __half*    bufH3   = bufS1;   // alias: mm3 writes row-major 64-col table into
                                  // bufS1 region (its sliced table already consumed)
    (void)ws_size;

    const int BLK = 256;
    const int nEB = (E + EDGE_CHUNK - 1) / EDGE_CHUNK;   // 196
    const int gMM = (N + 63) / 64;                       // 1563

    // 0) zero bucket cursors
    hipMemsetAsync(cursor, 0, (size_t)NB * sizeof(int), stream);
    // 1) fused: edge slab scatter  ∥  layer-1 matmul (x @ W1 -> sliced fp16 table)
    k_front<<<nEB + gMM, BLK, 0, stream>>>(src, dst, ea, cursor, stage, E,
                                           x, W1, bufS1, N, nEB);
    // 2) deg/dinv from slabs (+ bucket count scan)
    k_slabdeg<<<NB, 512, 0, stream>>>(stage, cursor, dinv, bbase, N, NB, E);
    // 3) fused: bucket CSR build (normalized weights)  ∥  W2/W3 fp16 convert
    k_csrw<<<NB + 96, BLK, 0, stream>>>(stage, bbase, dinv, row_ptr, csr, N, E,
                                        W2, W3, W2T, W3T, NB);

    const int gAGS = 8 * ((N + 3) / 4);     // sliced agg: 8 slices x (4 nodes/block)
    const int gAG3 = (N + 3) / 4;           // unsliced agg (layer 3)

    // layer 1: sliced agg -> sliced fp16 h1
    k_agg_s<true><<<gAGS, BLK, 0, stream>>>(bufS1, row_ptr, csr, dinv, b1, bufS2, N, N);
    // layer 2: mm (sliced A -> sliced C), sliced agg -> sliced h2
    k_mm_mfma<HID, true><<<gMM, BLK, 0, stream>>>((const _Float16*)bufS2, W2T, bufS1, N);
    k_agg_s<true><<<gAGS, BLK, 0, stream>>>(bufS1, row_ptr, csr, dinv, b2, bufS2, N, N);
    // layer 3: mm (sliced A -> row-major 64-col table), unsliced agg -> f32 d_out
    k_mm_mfma<N_CLS, false><<<gMM, BLK, 0, stream>>>((const _Float16*)bufS2, W3T, bufH3, N);
    k_agg<N_CLS, false><<<gAG3, BLK, 0, stream>>>(bufH3, row_ptr, csr, dinv, b3,
                                                  (float*)d_out, N);
}

// Round 12
// 280.009 us; speedup vs baseline: 2.2632x; 2.2632x over previous
//
#include <hip/hip_runtime.h>
#include <hip/hip_fp16.h>

// GCN (3× GCNConv, PyG semantics) on MI355X.
// Pipeline per call (8 dispatches):
//   0. hipMemsetAsync  - zero bucket cursors
//   1. k_front   - blocks [0,nEB): edge slab scatter (LDS hist + bump cursors)
//                  blocks [nEB,..): layer-1 MFMA matmul x@W1 (inline W1->fp16)
//   2. k_slabdeg - per-bucket deg accumulate -> dinv; block 0 scans counts->bbase
//   3. k_csrw    - blocks [0,NB): per-bucket LDS hist/scan -> row_ptr + CSR with
//                  normalized weight dinv[src]*w; blocks [NB,..): W2/W3 -> fp16T
//   4-8. agg1, mm2, agg2, mm3, agg3
// k_agg is at its structural floor: FETCH == table(25.6MB) x 8 XCD compulsory
// L2 fill at ~3.6 TB/s; insensitive to MLP (r4), scales with bytes (r6).
// r11 ablation: 16-col XCD-pinned slices DID cut FETCH 200->82MB but went
// instruction-bound (VALUBusy 46%, 4x slower) - per-wave work granularity
// must stay at a full row. Flat structure retained.

#define F_IN 128
#define HID  128
#define N_CLS 64

#define EDGE_CHUNK 8192   // edges per block in bscatter (32/thread)
#define BCAP 6144         // stage slab capacity per bucket (max count ~4400)

typedef _Float16 h8 __attribute__((ext_vector_type(8)));
typedef float f32x4 __attribute__((ext_vector_type(4)));

// ---------------- MFMA matmul body ----------------
// C[nrows][BN] (fp16) = A[nrows][128] @ W[128][BN], f32 accum.
// block = 64 rows, 4 waves x 16 rows. lw/lc carved from caller smem.
// CVTW: stage W from f32 k-major source (transpose+convert); else from fp16 WT.

template <int BN, typename TA, bool CVTW>
__device__ __forceinline__
void mm_body(const TA* __restrict__ A, const float* __restrict__ Wsrc,
             const _Float16* __restrict__ WT, __half* __restrict__ C,
             int nrows, int bid, char* smem) {
    constexpr int K   = 128;
    constexpr int NCT = BN / 16;          // col tiles per wave: 8 or 4
    constexpr int KP  = K + 8;            // LDS W row stride (halves)
    constexpr int CP  = BN + 8;           // LDS C row stride (halves)
    _Float16* lw = (_Float16*)smem;                       // BN*KP halves
    _Float16* lc = (_Float16*)(smem + (size_t)BN * KP * 2); // 64*CP halves
    const int tid  = threadIdx.x;
    const int wave = tid >> 6;
    const int lane = tid & 63;
    const int bm0  = bid * 64;

    if constexpr (CVTW) {
        // Wsrc[k][BN] f32 -> lw[n*KP+k] fp16 (coalesced reads: n fastest)
        for (int c = tid; c < BN * K; c += 256) {
            int n = c & (BN - 1);
            int k = c / BN;
            lw[n * KP + k] = (_Float16)Wsrc[k * BN + n];
        }
    } else {
        for (int c = tid; c < BN * 16; c += 256) {
            int n = c >> 4, k = (c & 15) * 8;
            *(h8*)&lw[n * KP + k] = *(const h8*)&WT[n * 128 + k];
        }
    }
    __syncthreads();

    f32x4 acc[NCT];
#pragma unroll
    for (int ct = 0; ct < NCT; ++ct)
#pragma unroll
        for (int i = 0; i < 4; ++i) acc[ct][i] = 0.0f;

    const int row = bm0 + wave * 16 + (lane & 15);
    const int kb  = (lane >> 4) * 8;
    const bool rok = row < nrows;

#pragma unroll
    for (int kk = 0; kk < 4; ++kk) {
        const int k0 = kk * 32 + kb;
        h8 va;
        if (rok) {
            if constexpr (__is_same(TA, float)) {
                float4 f0 = *(const float4*)&A[(size_t)row * K + k0];
                float4 f1 = *(const float4*)&A[(size_t)row * K + k0 + 4];
                va[0] = (_Float16)f0.x; va[1] = (_Float16)f0.y;
                va[2] = (_Float16)f0.z; va[3] = (_Float16)f0.w;
                va[4] = (_Float16)f1.x; va[5] = (_Float16)f1.y;
                va[6] = (_Float16)f1.z; va[7] = (_Float16)f1.w;
            } else {
                va = *(const h8*)&A[(size_t)row * K + k0];
            }
        } else {
#pragma unroll
            for (int i = 0; i < 8; ++i) va[i] = (_Float16)0.0f;
        }
#pragma unroll
        for (int ct = 0; ct < NCT; ++ct) {
            h8 vb = *(const h8*)&lw[(ct * 16 + (lane & 15)) * KP + k0];
            acc[ct] = __builtin_amdgcn_mfma_f32_16x16x32_f16(va, vb, acc[ct], 0, 0, 0);
        }
    }

    // stage C tile (fp16) in LDS, then coalesced copy-out
#pragma unroll
    for (int ct = 0; ct < NCT; ++ct)
#pragma unroll
        for (int r = 0; r < 4; ++r)
            lc[(wave * 16 + (lane >> 4) * 4 + r) * CP + ct * 16 + (lane & 15)] =
                (_Float16)acc[ct][r];
    __syncthreads();

    constexpr int NCH = (64 * BN / 8) / 256;   // 8-half chunks per thread
#pragma unroll
    for (int i = 0; i < NCH; ++i) {
        int c = i * 256 + tid;
        int r = c / (BN / 8), col = (c % (BN / 8)) * 8;
        int grow = bm0 + r;
        if (grow < nrows)
            *(h8*)&C[(size_t)grow * BN + col] = *(const h8*)&lc[r * CP + col];
    }
}

// ---------------- edge slab scatter body ----------------
// LDS hist -> global bump reservation -> place packed {src|dlow<<20, w}

__device__ __forceinline__
void bscatter_body(const int* __restrict__ src, const int* __restrict__ dst,
                   const float* __restrict__ w, int* __restrict__ cursor,
                   int2* __restrict__ stage, int E, int bid, char* smem) {
    int* lcnt  = (int*)smem;            // 512 ints
    int* lbase = (int*)(smem + 2048);   // 512 ints
    const int t = threadIdx.x;
    for (int i = t; i < 512; i += 256) lcnt[i] = 0;
    __syncthreads();
    const int base = bid * EDGE_CHUNK;
    int d[32];
#pragma unroll
    for (int i = 0; i < 32; ++i) {
        int e = base + i * 256 + t;
        d[i] = (e < E) ? dst[e] : -1;
        if (d[i] >= 0) atomicAdd(&lcnt[d[i] >> 8], 1);
    }
    __syncthreads();
    for (int i = t; i < 512; i += 256) {
        int c = lcnt[i];
        lbase[i] = (c > 0) ? atomicAdd(&cursor[i], c) : 0;
        lcnt[i] = 0;
    }
    __syncthreads();
#pragma unroll
    for (int i = 0; i < 32; ++i) {
        int e = base + i * 256 + t;
        if (e >= E) continue;
        int dd = d[i];
        int b  = dd >> 8;
        int p  = lbase[b] + atomicAdd(&lcnt[b], 1);
        if (p < BCAP)   // overflow guard (cannot trigger for this input)
            stage[(size_t)b * BCAP + p] =
                make_int2(src[e] | ((dd & 255) << 20), __float_as_int(w[e]));
    }
}

// ---------------- k_front: bscatter blocks + layer-1 matmul blocks ----------------

#define SMEM_FRONT ((HID * (128 + 8) + 64 * (HID + 8)) * 2)   // 52224 B (mm branch)

__launch_bounds__(256)
__global__ void k_front(const int* __restrict__ src, const int* __restrict__ dst,
                        const float* __restrict__ w, int* __restrict__ cursor,
                        int2* __restrict__ stage, int E,
                        const float* __restrict__ x, const float* __restrict__ W1,
                        __half* __restrict__ bufH, int nrows, int nEB) {
    __shared__ __align__(16) char smem[SMEM_FRONT];
    if ((int)blockIdx.x < nEB)
        bscatter_body(src, dst, w, cursor, stage, E, blockIdx.x, smem);
    else
        mm_body<HID, float, true>(x, W1, nullptr, bufH, nrows, blockIdx.x - nEB, smem);
}

// ---------------- k_slabdeg: deg/dinv from slabs (+ count scan in block 0) ----------------

__global__ void k_slabdeg(const int2* __restrict__ stage, const int* __restrict__ cursor,
                          float* __restrict__ dinv, int* __restrict__ bbase,
                          int n, int NB, int E) {
    __shared__ float degf[256];
    __shared__ int   sh[512];
    const int b = blockIdx.x, t = threadIdx.x;
    if (t < 256) degf[t] = 0.0f;
    __syncthreads();
    const int cnt0 = cursor[b];
    const int cnt  = (cnt0 < BCAP) ? cnt0 : BCAP;
    const int2* sl = stage + (size_t)b * BCAP;
    for (int j = t; j < cnt; j += 512) {
        int2 s = sl[j];
        atomicAdd(&degf[s.x >> 20], __int_as_float(s.y));
    }
    __syncthreads();
    const int node = b * 256 + t;
    if (t < 256 && node < n) dinv[node] = rsqrtf(1.0f + degf[t]);   // self-loop w=1

    if (b == 0) {   // exclusive scan of counts -> bbase (NB <= 512)
        sh[t] = (t < NB) ? min(cursor[t], BCAP) : 0;
        __syncthreads();
        for (int off = 1; off < 512; off <<= 1) {
            int x2 = (t >= off) ? sh[t - off] : 0;
            __syncthreads();
            sh[t] += x2;
            __syncthreads();
        }
        if (t < NB) bbase[t] = (t == 0) ? 0 : sh[t - 1];
        if (t == 0) bbase[NB] = E;
    }
}

// ---------------- k_csrw: bucket CSR build blocks + W2/W3 convert blocks ----------------

__launch_bounds__(256)
__global__ void k_csrw(const int2* __restrict__ stage, const int* __restrict__ bbase,
                       const float* __restrict__ dinv,
                       int* __restrict__ row_ptr, int2* __restrict__ csr,
                       int n, int E,
                       const float* __restrict__ W2, const float* __restrict__ W3,
                       _Float16* __restrict__ W2T, _Float16* __restrict__ W3T, int NB) {
    __shared__ int scn[256];
    __shared__ int cur[256];
    const int t = threadIdx.x;
    if ((int)blockIdx.x >= NB) {         // weight convert blocks
        int id = ((int)blockIdx.x - NB) * 256 + t;      // 0..24575
        if (id < 16384) {                // W2: 128x128
            int n2 = id >> 7, k = id & 127;
            W2T[n2 * 128 + k] = (_Float16)W2[k * 128 + n2];
        } else {                         // W3: 128x64
            int i = id - 16384;
            int n3 = i >> 7, k = i & 127;
            W3T[n3 * 128 + k] = (_Float16)W3[k * 64 + n3];
        }
        return;
    }
    const int b = blockIdx.x;
    const int beg = bbase[b];
    const int cnt = bbase[b + 1] - beg;
    const int2* sl = stage + (size_t)b * BCAP;
    scn[t] = 0;
    __syncthreads();
    for (int j = t; j < cnt; j += 256)
        atomicAdd(&scn[sl[j].x >> 20], 1);
    __syncthreads();
    int own = scn[t];
    __syncthreads();
    for (int off = 1; off < 256; off <<= 1) {          // inclusive scan
        int x2 = (t >= off) ? scn[t - off] : 0;
        __syncthreads();
        scn[t] += x2;
        __syncthreads();
    }
    const int excl = scn[t] - own;
    const int node = b * 256 + t;
    if (node < n) row_ptr[node] = beg + excl;
    cur[t] = excl;
    __syncthreads();
    for (int j = t; j < cnt; j += 256) {
        int2 s = sl[j];
        int dlow  = s.x >> 20;
        int srcid = s.x & 0xFFFFF;
        float nw  = dinv[srcid] * __int_as_float(s.y);
        int pos = beg + atomicAdd(&cur[dlow], 1);
        csr[pos] = make_int2(srcid, __float_as_int(nw));
    }
    if (b == 0 && t == 0) row_ptr[n] = E;
}

// ---------------- standalone matmul kernel (layers 2,3) ----------------

template <int BN, typename TA>
__launch_bounds__(256)
__global__ void k_mm_mfma(const TA* __restrict__ A, const _Float16* __restrict__ WT,
                          __half* __restrict__ C, int nrows) {
    __shared__ __align__(16) char smem[(BN * (128 + 8) + 64 * (BN + 8)) * 2];
    mm_body<BN, TA, false>(A, nullptr, WT, C, nrows, blockIdx.x, smem);
}

// ---------------- CSR aggregation (+ self-loop + bias [+ ReLU]) ----------------
// One 64-lane wave per destination node; fp16 gathers, f32 accumulate.
//   out = dn * (sum_j nw_j * x[s_j] + dn * x[node]) + bias

template <int NCOL, bool RELU, typename TO>
__launch_bounds__(256)
__global__ void k_agg(const __half* __restrict__ XW, const int* __restrict__ row_ptr,
                      const int2* __restrict__ csr,
                      const float* __restrict__ dinv, const float* __restrict__ bias,
                      TO* __restrict__ out, int n) {
    constexpr int PER = NCOL / 64;   // 2 (half2) or 1 (half)
    int wid  = (blockIdx.x * blockDim.x + threadIdx.x) >> 6;
    int lane = threadIdx.x & 63;
    if (wid >= n) return;
    const int node = __builtin_amdgcn_readfirstlane(wid);
    const float dn  = dinv[node];
    const int  beg  = row_ptr[node];
    const int  end  = row_ptr[node + 1];

    float a0, a1 = 0.0f;
    {   // self contribution: dn * x[node] (outer dn applied at the end)
        if (PER == 2) {
            __half2 hv = *(const __half2*)&XW[(size_t)node * NCOL + lane * 2];
            a0 = dn * __low2float(hv); a1 = dn * __high2float(hv);
        } else {
            a0 = dn * __half2float(XW[(size_t)node * NCOL + lane]);
        }
    }

    int j = beg;
    for (; j + 4 <= end; j += 4) {
        int2 e0 = csr[j + 0], e1 = csr[j + 1], e2 = csr[j + 2], e3 = csr[j + 3];
        float w0 = __int_as_float(e0.y), w1 = __int_as_float(e1.y);
        float w2 = __int_as_float(e2.y), w3 = __int_as_float(e3.y);
        if (PER == 2) {
            __half2 v0 = *(const __half2*)&XW[(size_t)e0.x * NCOL + lane * 2];
            __half2 v1 = *(const __half2*)&XW[(size_t)e1.x * NCOL + lane * 2];
            __half2 v2 = *(const __half2*)&XW[(size_t)e2.x * NCOL + lane * 2];
            __half2 v3 = *(const __half2*)&XW[(size_t)e3.x * NCOL + lane * 2];
            a0 = fmaf(w0, __low2float(v0), a0); a1 = fmaf(w0, __high2float(v0), a1);
            a0 = fmaf(w1, __low2float(v1), a0); a1 = fmaf(w1, __high2float(v1), a1);
            a0 = fmaf(w2, __low2float(v2), a0); a1 = fmaf(w2, __high2float(v2), a1);
            a0 = fmaf(w3, __low2float(v3), a0); a1 = fmaf(w3, __high2float(v3), a1);
        } else {
            float v0 = __half2float(XW[(size_t)e0.x * NCOL + lane]);
            float v1 = __half2float(XW[(size_t)e1.x * NCOL + lane]);
            float v2 = __half2float(XW[(size_t)e2.x * NCOL + lane]);
            float v3 = __half2float(XW[(size_t)e3.x * NCOL + lane]);
            a0 = fmaf(w0, v0, a0);
            a0 = fmaf(w1, v1, a0);
            a0 = fmaf(w2, v2, a0);
            a0 = fmaf(w3, v3, a0);
        }
    }
    for (; j < end; ++j) {
        int2 e = csr[j];
        float nw = __int_as_float(e.y);
        if (PER == 2) {
            __half2 v = *(const __half2*)&XW[(size_t)e.x * NCOL + lane * 2];
            a0 = fmaf(nw, __low2float(v), a0); a1 = fmaf(nw, __high2float(v), a1);
        } else {
            a0 = fmaf(nw, __half2float(XW[(size_t)e.x * NCOL + lane]), a0);
        }
    }

    if (PER == 2) {
        a0 = fmaf(dn, a0, bias[lane * 2 + 0]);
        a1 = fmaf(dn, a1, bias[lane * 2 + 1]);
        if (RELU) { a0 = fmaxf(a0, 0.0f); a1 = fmaxf(a1, 0.0f); }
        if constexpr (__is_same(TO, float)) {
            *(float2*)&out[(size_t)node * NCOL + lane * 2] = make_float2(a0, a1);
        } else {
            *(__half2*)&out[(size_t)node * NCOL + lane * 2] = __floats2half2_rn(a0, a1);
        }
    } else {
        a0 = fmaf(dn, a0, bias[lane]);
        if (RELU) a0 = fmaxf(a0, 0.0f);
        if constexpr (__is_same(TO, float)) {
            out[(size_t)node * NCOL + lane] = a0;
        } else {
            out[(size_t)node * NCOL + lane] = __float2half(a0);
        }
    }
}

// ---------------- launch ----------------

extern "C" void kernel_launch(void* const* d_in, const int* in_sizes, int n_in,
                              void* d_out, int out_size, void* d_ws, size_t ws_size,
                              hipStream_t stream) {
    const float* x  = (const float*)d_in[0];
    const int*   ei = (const int*)d_in[1];
    const float* ea = (const float*)d_in[2];
    const float* W1 = (const float*)d_in[3];
    const float* b1 = (const float*)d_in[4];
    const float* W2 = (const float*)d_in[5];
    const float* b2 = (const float*)d_in[6];
    const float* W3 = (const float*)d_in[7];
    const float* b3 = (const float*)d_in[8];

    const int N = in_sizes[0] / F_IN;   // 100000
    const int E = in_sizes[1] / 2;      // 1600000
    const int* src = ei;
    const int* dst = ei + E;
    const int NB = (N + 255) / 256;     // 391 buckets (<= 512 assumed)

    // workspace carve-up (256B aligned)
    char* ws = (char*)d_ws;
    size_t off = 0;
    auto alloc = [&](size_t bytes) -> void* {
        void* p = ws + off;
        off += (bytes + 255) & ~(size_t)255;
        return p;
    };
    __half*    bufH    = (__half*)   alloc((size_t)N * HID * sizeof(__half)); // XW fp16 table
    __half*    bufH2   = (__half*)   alloc((size_t)N * HID * sizeof(__half)); // agg fp16 out
    float*     dinv    = (float*)    alloc((size_t)N * sizeof(float));
    int*       row_ptr = (int*)      alloc((size_t)(N + 1) * sizeof(int));
    int2*      csr     = (int2*)     alloc((size_t)E * sizeof(int2));
    int2*      stage   = (int2*)     alloc((size_t)NB * BCAP * sizeof(int2)); // 19.2 MB slabs
    int*       cursor  = (int*)      alloc((size_t)NB * sizeof(int));
    int*       bbase   = (int*)      alloc((size_t)(NB + 1) * sizeof(int));
    _Float16*  W2T     = (_Float16*) alloc((size_t)128 * 128 * sizeof(_Float16));
    _Float16*  W3T     = (_Float16*) alloc((size_t)64 * 128 * sizeof(_Float16));
    (void)ws_size;

    const int BLK = 256;
    const int nEB = (E + EDGE_CHUNK - 1) / EDGE_CHUNK;   // 196
    const int gMM = (N + 63) / 64;                       // 1563

    // 0) zero bucket cursors
    hipMemsetAsync(cursor, 0, (size_t)NB * sizeof(int), stream);
    // 1) fused: edge slab scatter  ∥  layer-1 matmul (x @ W1 -> fp16 table)
    k_front<<<nEB + gMM, BLK, 0, stream>>>(src, dst, ea, cursor, stage, E,
                                           x, W1, bufH, N, nEB);
    // 2) deg/dinv from slabs (+ bucket count scan)
    k_slabdeg<<<NB, 512, 0, stream>>>(stage, cursor, dinv, bbase, N, NB, E);
    // 3) fused: bucket CSR build (normalized weights)  ∥  W2/W3 fp16 convert
    k_csrw<<<NB + 96, BLK, 0, stream>>>(stage, bbase, dinv, row_ptr, csr, N, E,
                                        W2, W3, W2T, W3T, NB);

    const int gAG = (N + 3) / 4;            // 4 waves/block, 1 wave/node

    // layer 1 agg -> fp16 h1
    k_agg<HID, true, __half><<<gAG, BLK, 0, stream>>>(bufH, row_ptr, csr, dinv, b1, bufH2, N);
    // layer 2
    k_mm_mfma<HID, __half><<<gMM, BLK, 0, stream>>>(bufH2, W2T, bufH, N);
    k_agg<HID, true, __half><<<gAG, BLK, 0, stream>>>(bufH, row_ptr, csr, dinv, b2, bufH2, N);
    // layer 3 -> f32 d_out
    k_mm_mfma<N_CLS, __half><<<gMM, BLK, 0, stream>>>(bufH2, W3T, bufH, N);
    k_agg<N_CLS, false, float><<<gAG, BLK, 0, stream>>>(bufH, row_ptr, csr, dinv, b3, (float*)d_out, N);
}